// Round 3
// baseline (655.354 us; speedup 1.0000x reference)
//
#include <hip/hip_runtime.h>

#define Bq 2
#define Yq 512
#define Xq 512

typedef __bf16 bf16x8 __attribute__((ext_vector_type(8)));
typedef float f32x4 __attribute__((ext_vector_type(4)));
typedef float f32x16 __attribute__((ext_vector_type(16)));
typedef short s16x8 __attribute__((ext_vector_type(8)));

__device__ __forceinline__ short f2bf_s(float f){
    return __builtin_bit_cast(short, static_cast<__bf16>(f));
}

// ---------------- weight transpose + bf16 convert ----------------
// wT[tap][cout][cin]  <- conv_w[ky][kx][cin][cout]   (9*128*128)
// wpT[cout][cin]      <- W_proj[cin][cout]           (128*192)
__global__ void kprep(const float* __restrict__ conv_w, const float* __restrict__ W_proj,
                      short* __restrict__ wT, short* __restrict__ wpT){
    int tid = blockIdx.x*256 + threadIdx.x;
    if (tid < 9*128*128){
        int tap = tid >> 14; int r = tid & 16383; int co = r >> 7; int ci = r & 127;
        wT[tid] = f2bf_s(conv_w[tap*16384 + ci*128 + co]);
    }
    int e = tid - 9*128*128;
    if (e >= 0 && e < 128*192){
        int co = e / 192; int ci = e - co*192;
        wpT[e] = f2bf_s(W_proj[ci*128 + co]);
    }
}

// ---------------- projection + BN1 + ReLU + scatter (unchanged) ----------------
__global__ void __launch_bounds__(256, 2)
kproj(const float* __restrict__ vf, const int* __restrict__ vc,
      const short* __restrict__ wpT, const float* __restrict__ bp,
      const float* __restrict__ g1, const float* __restrict__ be1,
      const float* __restrict__ mu1, const float* __restrict__ va1,
      float* __restrict__ dense, unsigned char* __restrict__ act){
    __shared__ short A[64*200];
    __shared__ int cells[64];
    const int t = threadIdx.x;
    const int v0 = blockIdx.x * 64;

    const float4* vf4 = reinterpret_cast<const float4*>(vf);
    #pragma unroll
    for (int j = 0; j < 12; ++j){
        int i = t + j*256;
        int v = i / 48, kq = i - v*48;
        float4 x = vf4[(size_t)(v0 + v)*48 + kq];
        short4 s; s.x=f2bf_s(x.x); s.y=f2bf_s(x.y); s.z=f2bf_s(x.z); s.w=f2bf_s(x.w);
        *reinterpret_cast<short4*>(&A[v*200 + kq*4]) = s;
    }
    if (t < 64){
        int vi = v0 + t;
        int bi = vc[vi*4 + 0], yi = vc[vi*4 + 2], xi = vc[vi*4 + 3];
        int cell = (bi*Yq + yi)*Xq + xi;
        cells[t] = cell;
        act[cell] = 1;
    }
    __syncthreads();

    const int w  = t >> 6;
    const int l  = t & 63;
    const int lr = l & 15;
    const int q  = l >> 4;

    const short* wp_lane = wpT + (size_t)(w*32 + lr)*192 + q*8;
    bf16x8 bb[2][6];
    #pragma unroll
    for (int n = 0; n < 2; ++n)
        #pragma unroll
        for (int kc = 0; kc < 6; ++kc)
            bb[n][kc] = *reinterpret_cast<const bf16x8*>(wp_lane + n*16*192 + kc*32);

    f32x4 acc[4][2] = {};
    #pragma unroll
    for (int kc = 0; kc < 6; ++kc){
        bf16x8 a[4];
        #pragma unroll
        for (int m = 0; m < 4; ++m)
            a[m] = *reinterpret_cast<const bf16x8*>(&A[(m*16 + lr)*200 + kc*32 + q*8]);
        #pragma unroll
        for (int m = 0; m < 4; ++m)
            #pragma unroll
            for (int n = 0; n < 2; ++n)
                acc[m][n] = __builtin_amdgcn_mfma_f32_16x16x32_bf16(a[m], bb[n][kc], acc[m][n], 0, 0, 0);
    }

    #pragma unroll
    for (int n = 0; n < 2; ++n){
        int c = w*32 + n*16 + lr;
        float s1  = g1[c] * rsqrtf(va1[c] + 1e-5f);
        float sh1 = be1[c] + (bp[c] - mu1[c]) * s1;
        #pragma unroll
        for (int m = 0; m < 4; ++m){
            #pragma unroll
            for (int r = 0; r < 4; ++r){
                int v = m*16 + q*4 + r;
                float val = fmaxf(fmaf(acc[m][n][r], s1, sh1), 0.f);
                atomicAdd(&dense[(size_t)cells[v]*128 + c], val);
            }
        }
    }
}

// ---------------- pad + fp32 -> bf16 convert, PRE-SWIZZLED ----------------
// dbf: [B][514][514] rows of 16 16B-slots; value (xp, c8) stored at slot
// P*16 + (c8 ^ (xp&7)).  Linear global_load_lds then yields the swizzled
// LDS layout kconv's ds_read_b128 needs for conflict-free banks.
__global__ void kcvt(const float* __restrict__ dense, short* __restrict__ dbf){
    int i = blockIdx.x*256 + threadIdx.x;
    if (i >= 2*514*514*16) return;
    int P = i >> 4; int c8 = i & 15;
    int b  = P / (514*514); int rr = P - b*(514*514);
    int yp = rr / 514; int xp = rr - yp*514;
    s16x8 o = {0,0,0,0,0,0,0,0};
    if (yp >= 1 && yp <= 512 && xp >= 1 && xp <= 512){
        const float4* s = reinterpret_cast<const float4*>(
            &dense[((size_t)((b*Yq + (yp-1))*Xq) + (xp-1))*128 + c8*8]);
        float4 f0 = s[0], f1 = s[1];
        o[0]=f2bf_s(f0.x); o[1]=f2bf_s(f0.y); o[2]=f2bf_s(f0.z); o[3]=f2bf_s(f0.w);
        o[4]=f2bf_s(f1.x); o[5]=f2bf_s(f1.y); o[6]=f2bf_s(f1.z); o[7]=f2bf_s(f1.w);
    }
    *reinterpret_cast<s16x8*>(&dbf[((size_t)P*16 + (c8 ^ (xp & 7)))*8]) = o;
}

// ---------------- conv 3x3 + BN2 + ReLU + mask ----------------
// block: 64 pos x 128 cout, 4 waves, wave tile 64pos x 32cout (m2 n1), MFMA 32x32x16
// A: all 3 rows staged once via global_load_lds (50.7KB -> 3 blocks/CU), 1 barrier
// B: per-tap register double-buffer from L2
__global__ void __launch_bounds__(256, 3)
kconv(const short* __restrict__ dbf, const short* __restrict__ wT,
      const unsigned char* __restrict__ act, const float* __restrict__ cb,
      const float* __restrict__ g2, const float* __restrict__ be2,
      const float* __restrict__ mu2, const float* __restrict__ va2,
      float* __restrict__ out){
    __shared__ short Atile[3*1056*8];   // 3 rows x 66 pos x 16 slots x 16B = 50,688B
    const int t = threadIdx.x;
    // bijective XCD swizzle: 8192 blocks, 1024/XCD; y-neighbors share a chunk
    const int bid = (blockIdx.x & 7)*1024 + (blockIdx.x >> 3);
    const int b   = bid >> 12;
    const int rem = bid & 4095;
    const int y   = rem >> 3;         // output row (padded rows y..y+2)
    const int x0  = (rem & 7) << 6;   // padded window start == output x base

    const int w   = t >> 6, l = t & 63;
    const int l31 = l & 31, hi = l >> 5;

    // ---- stage 3 rows (3168 16B-slots) via global_load_lds ----
    #pragma unroll
    for (int j = 0; j < 13; ++j){
        int S = j*256 + t;
        if (S < 3168){
            int r = S / 1056, s = S - r*1056;
            const short* gp = dbf + ((size_t)((b*514 + (y + r))*514 + x0)*16 + s)*8;
            char* lp = (char*)Atile + (size_t)(j*256 + w*64)*16;
            __builtin_amdgcn_global_load_lds(
                (const __attribute__((address_space(1))) void*)gp,
                (__attribute__((address_space(3))) void*)lp, 16, 0, 0);
        }
    }
    __syncthreads();

    const short* wt_lane = wT + (size_t)(w*32 + l31)*128 + hi*8;

    f32x16 acc0 = {}, acc1 = {};
    bf16x8 bB[2][8];
    #pragma unroll
    for (int kc = 0; kc < 8; ++kc)
        bB[0][kc] = *reinterpret_cast<const bf16x8*>(wt_lane + kc*16);

    #pragma unroll
    for (int tap = 0; tap < 9; ++tap){
        const int cur = tap & 1;
        if (tap < 8){
            const short* wn = wt_lane + (tap+1)*16384;
            #pragma unroll
            for (int kc = 0; kc < 8; ++kc)
                bB[cur^1][kc] = *reinterpret_cast<const bf16x8*>(wn + kc*16);
        }
        const int ky = tap / 3, kx = tap - ky*3;
        const int p0 = l31 + kx;          // mi=0 position row in tile
        const int p1 = p0 + 32;           // mi=1
        const int pk = p0 & 7;            // == p1 & 7
        const int s0 = (ky*1056 + p0*16)*8;
        const int s1 = (ky*1056 + p1*16)*8;
        #pragma unroll
        for (int kc = 0; kc < 8; ++kc){
            const int q = ((kc*2 + hi) ^ pk) << 3;
            bf16x8 a0 = *reinterpret_cast<const bf16x8*>(&Atile[s0 + q]);
            bf16x8 a1 = *reinterpret_cast<const bf16x8*>(&Atile[s1 + q]);
            acc0 = __builtin_amdgcn_mfma_f32_32x32x16_bf16(a0, bB[cur][kc], acc0, 0, 0, 0);
            acc1 = __builtin_amdgcn_mfma_f32_32x32x16_bf16(a1, bB[cur][kc], acc1, 0, 0, 0);
        }
    }

    // epilogue: BN2 + ReLU + mask; D: col=l31 (cout), row=(r&3)+8*(r>>2)+4*hi
    const int c = w*32 + l31;
    const float s2  = g2[c] * rsqrtf(va2[c] + 1e-3f);
    const float sh2 = be2[c] + (cb[c] - mu2[c]) * s2;
    const size_t rowcell = (size_t)(b*Yq + y)*Xq + x0;
    #pragma unroll
    for (int mi = 0; mi < 2; ++mi){
        const f32x16& a = mi ? acc1 : acc0;
        #pragma unroll
        for (int r = 0; r < 16; ++r){
            int pos = mi*32 + (r & 3) + ((r >> 2) << 3) + hi*4;
            size_t cell = rowcell + pos;
            float v = act[cell] ? fmaxf(fmaf(a[r], s2, sh2), 0.f) : 0.f;
            out[cell*128 + c] = v;
        }
    }
}

extern "C" void kernel_launch(void* const* d_in, const int* in_sizes, int n_in,
                              void* d_out, int out_size, void* d_ws, size_t ws_size,
                              hipStream_t stream){
    const float* vf  = (const float*)d_in[0];
    const int*   vc  = (const int*)  d_in[1];
    const float* Wp  = (const float*)d_in[2];
    const float* bp  = (const float*)d_in[3];
    const float* g1  = (const float*)d_in[4];
    const float* be1 = (const float*)d_in[5];
    const float* mu1 = (const float*)d_in[6];
    const float* va1 = (const float*)d_in[7];
    const float* cw  = (const float*)d_in[8];
    const float* cb  = (const float*)d_in[9];
    const float* g2  = (const float*)d_in[10];
    const float* be2 = (const float*)d_in[11];
    const float* mu2 = (const float*)d_in[12];
    const float* va2 = (const float*)d_in[13];
    float* out = (float*)d_out;
    char* ws = (char*)d_ws;

    // ws layout (bytes):
    //   dense fp32 [2][512][512][128]   : 268,435,456 @ 0
    //   dbf bf16   [2][514][514][128]   : 135,268,352 @ 268,435,456  (pre-swizzled)
    //   act  u8    [2][512][512]        :     524,288 @ 403,703,808
    //   wT   bf16  [9][128][128]        :     294,912 @ 404,228,096
    //   wpT  bf16  [128][192]           :      49,152 @ 404,523,008  (end 404,572,160)
    if (ws_size < 404572160ull) return;
    float* dense = (float*)ws;
    short* dbf   = (short*)(ws + 268435456);
    unsigned char* act = (unsigned char*)(ws + 403703808);
    short* wT    = (short*)(ws + 404228096);
    short* wpT   = (short*)(ws + 404523008);

    hipMemsetAsync(dense, 0, 268435456, stream);
    hipMemsetAsync(act, 0, 524288, stream);
    kprep<<<672, 256, 0, stream>>>(cw, Wp, wT, wpT);
    kproj<<<6250, 256, 0, stream>>>(vf, vc, wpT, bp, g1, be1, mu1, va1, dense, act);
    kcvt<<<33025, 256, 0, stream>>>(dense, dbf);
    kconv<<<8192, 256, 0, stream>>>(dbf, wT, act, cb, g2, be2, mu2, va2, out);
}

// Round 4
// 529.170 us; speedup vs baseline: 1.2385x; 1.2385x over previous
//
#include <hip/hip_runtime.h>

#define Bq 2
#define Yq 512
#define Xq 512

typedef __bf16 bf16x8 __attribute__((ext_vector_type(8)));
typedef float f32x4 __attribute__((ext_vector_type(4)));
typedef float f32x16 __attribute__((ext_vector_type(16)));
typedef short s16x8 __attribute__((ext_vector_type(8)));
typedef short s16x2 __attribute__((ext_vector_type(2)));

__device__ __forceinline__ short f2bf_s(float f){
    return __builtin_bit_cast(short, static_cast<__bf16>(f));
}
__device__ __forceinline__ float bfbits2f(unsigned short u){
    unsigned v = ((unsigned)u) << 16; return __builtin_bit_cast(float, v);
}

__device__ __forceinline__ void atomic_pk_add_bf16(short* addr, short lo, short hi){
#if __has_builtin(__builtin_amdgcn_global_atomic_fadd_v2bf16)
    s16x2 v; v[0] = lo; v[1] = hi;
    __builtin_amdgcn_global_atomic_fadd_v2bf16(
        (__attribute__((address_space(1))) s16x2*)addr, v);
#else
    unsigned* p = (unsigned*)addr;
    float flo = bfbits2f((unsigned short)lo), fhi = bfbits2f((unsigned short)hi);
    unsigned old = *p, seen;
    do {
        seen = old;
        unsigned short olo = (unsigned short)(seen & 0xffff);
        unsigned short ohi = (unsigned short)(seen >> 16);
        unsigned short nlo = (unsigned short)f2bf_s(bfbits2f(olo) + flo);
        unsigned short nhi = (unsigned short)f2bf_s(bfbits2f(ohi) + fhi);
        unsigned nv = ((unsigned)nhi << 16) | nlo;
        old = atomicCAS(p, seen, nv);
    } while (old != seen);
#endif
}

// ---------------- weight transpose + bf16 convert ----------------
// wT[tap][cout][cin]  <- conv_w[ky][kx][cin][cout]   (9*128*128)
// wpT[cout][cin]      <- W_proj[cin][cout]           (128*192)
__global__ void kprep(const float* __restrict__ conv_w, const float* __restrict__ W_proj,
                      short* __restrict__ wT, short* __restrict__ wpT){
    int tid = blockIdx.x*256 + threadIdx.x;
    if (tid < 9*128*128){
        int tap = tid >> 14; int r = tid & 16383; int co = r >> 7; int ci = r & 127;
        wT[tid] = f2bf_s(conv_w[tap*16384 + ci*128 + co]);
    }
    int e = tid - 9*128*128;
    if (e >= 0 && e < 128*192){
        int co = e / 192; int ci = e - co*192;
        wpT[e] = f2bf_s(W_proj[ci*128 + co]);
    }
}

// ---------------- projection + BN1 + ReLU + bf16 pk-atomic scatter ----------
// Scatters DIRECTLY into padded pre-swizzled dbf; no fp32 dense buffer.
__global__ void __launch_bounds__(256, 2)
kproj(const float* __restrict__ vf, const int* __restrict__ vc,
      const short* __restrict__ wpT, const float* __restrict__ bp,
      const float* __restrict__ g1, const float* __restrict__ be1,
      const float* __restrict__ mu1, const float* __restrict__ va1,
      short* __restrict__ dbf, unsigned char* __restrict__ act){
    __shared__ short A[64*200];
    __shared__ int cellsPk[64];     // P*8 + (xp&7)
    const int t = threadIdx.x;
    const int v0 = blockIdx.x * 64;

    const float4* vf4 = reinterpret_cast<const float4*>(vf);
    #pragma unroll
    for (int j = 0; j < 12; ++j){
        int i = t + j*256;
        int v = i / 48, kq = i - v*48;
        float4 x = vf4[(size_t)(v0 + v)*48 + kq];
        short4 s; s.x=f2bf_s(x.x); s.y=f2bf_s(x.y); s.z=f2bf_s(x.z); s.w=f2bf_s(x.w);
        *reinterpret_cast<short4*>(&A[v*200 + kq*4]) = s;
    }
    if (t < 64){
        int vi = v0 + t;
        int bi = vc[vi*4 + 0], yi = vc[vi*4 + 2], xi = vc[vi*4 + 3];
        act[(bi*Yq + yi)*Xq + xi] = 1;
        int P = (bi*514 + (yi + 1))*514 + (xi + 1);
        cellsPk[t] = P*8 + ((xi + 1) & 7);
    }
    __syncthreads();

    const int w  = t >> 6;
    const int l  = t & 63;
    const int lr = l & 15;
    const int q  = l >> 4;

    const short* wp_lane = wpT + (size_t)(w*32 + lr)*192 + q*8;
    bf16x8 bb[2][6];
    #pragma unroll
    for (int n = 0; n < 2; ++n)
        #pragma unroll
        for (int kc = 0; kc < 6; ++kc)
            bb[n][kc] = *reinterpret_cast<const bf16x8*>(wp_lane + n*16*192 + kc*32);

    f32x4 acc[4][2] = {};
    #pragma unroll
    for (int kc = 0; kc < 6; ++kc){
        bf16x8 a[4];
        #pragma unroll
        for (int m = 0; m < 4; ++m)
            a[m] = *reinterpret_cast<const bf16x8*>(&A[(m*16 + lr)*200 + kc*32 + q*8]);
        #pragma unroll
        for (int m = 0; m < 4; ++m)
            #pragma unroll
            for (int n = 0; n < 2; ++n)
                acc[m][n] = __builtin_amdgcn_mfma_f32_16x16x32_bf16(a[m], bb[n][kc], acc[m][n], 0, 0, 0);
    }

    // epilogue: BN1 + ReLU; lane-pair shuffle -> packed bf16 atomic scatter
    #pragma unroll
    for (int n = 0; n < 2; ++n){
        int c = w*32 + n*16 + lr;
        float s1  = g1[c] * rsqrtf(va1[c] + 1e-5f);
        float sh1 = be1[c] + (bp[c] - mu1[c]) * s1;
        #pragma unroll
        for (int m = 0; m < 4; ++m){
            #pragma unroll
            for (int r = 0; r < 4; ++r){
                int vx = m*16 + q*4 + r;
                float val = fmaxf(fmaf(acc[m][n][r], s1, sh1), 0.f);
                float vp  = __shfl_xor(val, 1);
                if ((lr & 1) == 0 && (val != 0.f || vp != 0.f)){
                    int pk = cellsPk[vx];
                    int P = pk >> 3, xp7 = pk & 7;
                    short* addr = dbf + (size_t)P*128 + (((c >> 3) ^ xp7) << 3) + (c & 7);
                    atomic_pk_add_bf16(addr, f2bf_s(val), f2bf_s(vp));
                }
            }
        }
    }
}

// ---------------- conv 3x3 + BN2 + ReLU + mask ----------------
// block: 2 y-rows x 64 x x 128 cout; 4 waves = (yy, nn); wave tile 64pos x 64cout
// (m2 x n2, MFMA 32x32x16).  A: 4 padded rows staged once via global_load_lds
// (67.6KB -> 2 blocks/CU).  B: per-tap register dbuf, pinned by sched_barrier.
__global__ void __launch_bounds__(256, 2)
kconv(const short* __restrict__ dbf, const short* __restrict__ wT,
      const unsigned char* __restrict__ act, const float* __restrict__ cb,
      const float* __restrict__ g2, const float* __restrict__ be2,
      const float* __restrict__ mu2, const float* __restrict__ va2,
      float* __restrict__ out){
    __shared__ short Atile[4*1056*8];   // 4 rows x 66 pos x 16 slots x 16B = 67,584B
    const int t = threadIdx.x;
    // bijective XCD swizzle: 4096 blocks, 512/XCD
    const int bid = (blockIdx.x & 7)*512 + (blockIdx.x >> 3);
    const int b   = bid >> 11;
    const int rem = bid & 2047;
    const int y0  = (rem >> 3) << 1;   // output row pair y0, y0+1
    const int x0  = (rem & 7) << 6;

    const int w   = t >> 6, l = t & 63;
    const int yy  = w >> 1, nn = w & 1;
    const int l31 = l & 31, hi = l >> 5;

    // stage 4 padded rows (4224 16B-slots) via global_load_lds
    #pragma unroll
    for (int j = 0; j < 17; ++j){
        int S = j*256 + t;
        if (S < 4224){
            int r = S / 1056, s = S - r*1056;
            const short* gp = dbf + ((size_t)((b*514 + (y0 + r))*514 + x0)*16 + s)*8;
            char* lp = (char*)Atile + (size_t)(j*256 + w*64)*16;
            __builtin_amdgcn_global_load_lds(
                (const __attribute__((address_space(1))) void*)gp,
                (__attribute__((address_space(3))) void*)lp, 16, 0, 0);
        }
    }
    __syncthreads();

    const short* wt_lane = wT + (size_t)(nn*64 + l31)*128 + hi*8;

    f32x16 acc[2][2] = {};     // [mi][ni]
    bf16x8 bb[2][2][8];        // [pipe][ni][kc]
    #pragma unroll
    for (int ni = 0; ni < 2; ++ni)
        #pragma unroll
        for (int kc = 0; kc < 8; ++kc)
            bb[0][ni][kc] = *reinterpret_cast<const bf16x8*>(wt_lane + ni*4096 + kc*16);

    #pragma unroll
    for (int tap = 0; tap < 9; ++tap){
        const int cur = tap & 1;
        if (tap < 8){
            const short* wn = wt_lane + (size_t)(tap+1)*16384;
            #pragma unroll
            for (int ni = 0; ni < 2; ++ni)
                #pragma unroll
                for (int kc = 0; kc < 8; ++kc)
                    bb[cur^1][ni][kc] = *reinterpret_cast<const bf16x8*>(wn + ni*4096 + kc*16);
        }
        __builtin_amdgcn_sched_barrier(0);   // pin prefetch issue above the MFMAs
        const int ky = tap / 3, kx = tap - ky*3;
        const int row = yy + ky;
        const int p0 = l31 + kx, p1 = p0 + 32;
        const int base0 = (row*1056 + p0*16)*8;
        const int base1 = (row*1056 + p1*16)*8;
        const int pk7 = p0 & 7;              // == p1 & 7
        #pragma unroll
        for (int kc = 0; kc < 8; ++kc){
            const int q = ((kc*2 + hi) ^ pk7) << 3;
            bf16x8 a0 = *reinterpret_cast<const bf16x8*>(&Atile[base0 + q]);
            bf16x8 a1 = *reinterpret_cast<const bf16x8*>(&Atile[base1 + q]);
            acc[0][0] = __builtin_amdgcn_mfma_f32_32x32x16_bf16(a0, bb[cur][0][kc], acc[0][0], 0, 0, 0);
            acc[0][1] = __builtin_amdgcn_mfma_f32_32x32x16_bf16(a0, bb[cur][1][kc], acc[0][1], 0, 0, 0);
            acc[1][0] = __builtin_amdgcn_mfma_f32_32x32x16_bf16(a1, bb[cur][0][kc], acc[1][0], 0, 0, 0);
            acc[1][1] = __builtin_amdgcn_mfma_f32_32x32x16_bf16(a1, bb[cur][1][kc], acc[1][1], 0, 0, 0);
        }
    }

    // epilogue: BN2 + ReLU + mask; D: col=l31 (cout), row=(r&3)+8*(r>>2)+4*hi
    const int yg = y0 + yy;
    const size_t rowcell = (size_t)(b*Yq + yg)*Xq + x0;
    #pragma unroll
    for (int ni = 0; ni < 2; ++ni){
        int c = nn*64 + ni*32 + l31;
        float s2  = g2[c] * rsqrtf(va2[c] + 1e-3f);
        float sh2 = be2[c] + (cb[c] - mu2[c]) * s2;
        #pragma unroll
        for (int mi = 0; mi < 2; ++mi){
            #pragma unroll
            for (int r = 0; r < 16; ++r){
                int pos = mi*32 + (r & 3) + ((r >> 2) << 3) + hi*4;
                size_t cell = rowcell + pos;
                float v = act[cell] ? fmaxf(fmaf(acc[mi][ni][r], s2, sh2), 0.f) : 0.f;
                out[cell*128 + c] = v;
            }
        }
    }
}

extern "C" void kernel_launch(void* const* d_in, const int* in_sizes, int n_in,
                              void* d_out, int out_size, void* d_ws, size_t ws_size,
                              hipStream_t stream){
    const float* vf  = (const float*)d_in[0];
    const int*   vc  = (const int*)  d_in[1];
    const float* Wp  = (const float*)d_in[2];
    const float* bp  = (const float*)d_in[3];
    const float* g1  = (const float*)d_in[4];
    const float* be1 = (const float*)d_in[5];
    const float* mu1 = (const float*)d_in[6];
    const float* va1 = (const float*)d_in[7];
    const float* cw  = (const float*)d_in[8];
    const float* cb  = (const float*)d_in[9];
    const float* g2  = (const float*)d_in[10];
    const float* be2 = (const float*)d_in[11];
    const float* mu2 = (const float*)d_in[12];
    const float* va2 = (const float*)d_in[13];
    float* out = (float*)d_out;
    char* ws = (char*)d_ws;

    // ws layout (bytes):
    //   dbf bf16 [2][514][514][128] : 135,268,352 @ 0   (padded, pre-swizzled)
    //   act  u8  [2][512][512]      :     524,288 @ 135,268,352
    //   wT   bf16 [9][128][128]     :     294,912 @ 135,792,640
    //   wpT  bf16 [128][192]        :      49,152 @ 136,087,552  (end 136,136,704)
    if (ws_size < 136136704ull) return;
    short* dbf = (short*)ws;
    unsigned char* act = (unsigned char*)(ws + 135268352);
    short* wT  = (short*)(ws + 135792640);
    short* wpT = (short*)(ws + 136087552);

    hipMemsetAsync(dbf, 0, 135268352, stream);
    hipMemsetAsync(act, 0, 524288, stream);
    kprep<<<672, 256, 0, stream>>>(cw, Wp, wT, wpT);
    kproj<<<6250, 256, 0, stream>>>(vf, vc, wpT, bp, g1, be1, mu1, va1, dbf, act);
    kconv<<<4096, 256, 0, stream>>>(dbf, wT, act, cb, g2, be2, mu2, va2, out);
}

// Round 5
// 430.755 us; speedup vs baseline: 1.5214x; 1.2285x over previous
//
#include <hip/hip_runtime.h>

#define Bq 2
#define Yq 512
#define Xq 512

typedef __bf16 bf16x8 __attribute__((ext_vector_type(8)));
typedef float f32x4 __attribute__((ext_vector_type(4)));
typedef float f32x16 __attribute__((ext_vector_type(16)));
typedef short s16x8 __attribute__((ext_vector_type(8)));
typedef short s16x2 __attribute__((ext_vector_type(2)));

__device__ __forceinline__ short f2bf_s(float f){
    return __builtin_bit_cast(short, static_cast<__bf16>(f));
}
__device__ __forceinline__ float bfbits2f(unsigned short u){
    unsigned v = ((unsigned)u) << 16; return __builtin_bit_cast(float, v);
}

__device__ __forceinline__ void atomic_pk_add_bf16(short* addr, short lo, short hi){
#if __has_builtin(__builtin_amdgcn_global_atomic_fadd_v2bf16)
    s16x2 v; v[0] = lo; v[1] = hi;
    __builtin_amdgcn_global_atomic_fadd_v2bf16(
        (__attribute__((address_space(1))) s16x2*)addr, v);
#else
    unsigned* p = (unsigned*)addr;
    float flo = bfbits2f((unsigned short)lo), fhi = bfbits2f((unsigned short)hi);
    unsigned old = *p, seen;
    do {
        seen = old;
        unsigned short olo = (unsigned short)(seen & 0xffff);
        unsigned short ohi = (unsigned short)(seen >> 16);
        unsigned short nlo = (unsigned short)f2bf_s(bfbits2f(olo) + flo);
        unsigned short nhi = (unsigned short)f2bf_s(bfbits2f(ohi) + fhi);
        unsigned nv = ((unsigned)nhi << 16) | nlo;
        old = atomicCAS(p, seen, nv);
    } while (old != seen);
#endif
}

// ---------------- weight transpose + bf16 convert ----------------
// wTs[tap][cout][slot]: PRE-SWIZZLED for LDS — 8-cin group g of cout stored at
// group-slot g ^ (cout&7), so linear global_load_lds gives conflict-free
// ds_read_b128 in kconv.
// wpT[cout][cin] <- W_proj[cin][cout]  (unswizzled; kproj reads registers)
__global__ void kprep(const float* __restrict__ conv_w, const float* __restrict__ W_proj,
                      short* __restrict__ wTs, short* __restrict__ wpT){
    int tid = blockIdx.x*256 + threadIdx.x;
    if (tid < 9*128*128){
        int tap = tid >> 14; int r = tid & 16383; int co = r >> 7; int ci = r & 127;
        int g = ci >> 3, e = ci & 7;
        wTs[tap*16384 + co*128 + ((g ^ (co & 7)) << 3) + e] =
            f2bf_s(conv_w[tap*16384 + ci*128 + co]);
    }
    int e = tid - 9*128*128;
    if (e >= 0 && e < 128*192){
        int co = e / 192; int ci = e - co*192;
        wpT[e] = f2bf_s(W_proj[ci*128 + co]);
    }
}

// ---------------- projection + BN1 + ReLU + bf16 pk-atomic scatter ----------
__global__ void __launch_bounds__(256, 2)
kproj(const float* __restrict__ vf, const int* __restrict__ vc,
      const short* __restrict__ wpT, const float* __restrict__ bp,
      const float* __restrict__ g1, const float* __restrict__ be1,
      const float* __restrict__ mu1, const float* __restrict__ va1,
      short* __restrict__ dbf, unsigned char* __restrict__ act){
    __shared__ short A[64*200];
    __shared__ int cellsPk[64];     // P*8 + (xp&7)
    const int t = threadIdx.x;
    const int v0 = blockIdx.x * 64;

    const float4* vf4 = reinterpret_cast<const float4*>(vf);
    #pragma unroll
    for (int j = 0; j < 12; ++j){
        int i = t + j*256;
        int v = i / 48, kq = i - v*48;
        float4 x = vf4[(size_t)(v0 + v)*48 + kq];
        short4 s; s.x=f2bf_s(x.x); s.y=f2bf_s(x.y); s.z=f2bf_s(x.z); s.w=f2bf_s(x.w);
        *reinterpret_cast<short4*>(&A[v*200 + kq*4]) = s;
    }
    if (t < 64){
        int vi = v0 + t;
        int bi = vc[vi*4 + 0], yi = vc[vi*4 + 2], xi = vc[vi*4 + 3];
        act[(bi*Yq + yi)*Xq + xi] = 1;
        int P = (bi*514 + (yi + 1))*514 + (xi + 1);
        cellsPk[t] = P*8 + ((xi + 1) & 7);
    }
    __syncthreads();

    const int w  = t >> 6;
    const int l  = t & 63;
    const int lr = l & 15;
    const int q  = l >> 4;

    const short* wp_lane = wpT + (size_t)(w*32 + lr)*192 + q*8;
    bf16x8 bb[2][6];
    #pragma unroll
    for (int n = 0; n < 2; ++n)
        #pragma unroll
        for (int kc = 0; kc < 6; ++kc)
            bb[n][kc] = *reinterpret_cast<const bf16x8*>(wp_lane + n*16*192 + kc*32);

    f32x4 acc[4][2] = {};
    #pragma unroll
    for (int kc = 0; kc < 6; ++kc){
        bf16x8 a[4];
        #pragma unroll
        for (int m = 0; m < 4; ++m)
            a[m] = *reinterpret_cast<const bf16x8*>(&A[(m*16 + lr)*200 + kc*32 + q*8]);
        #pragma unroll
        for (int m = 0; m < 4; ++m)
            #pragma unroll
            for (int n = 0; n < 2; ++n)
                acc[m][n] = __builtin_amdgcn_mfma_f32_16x16x32_bf16(a[m], bb[n][kc], acc[m][n], 0, 0, 0);
    }

    #pragma unroll
    for (int n = 0; n < 2; ++n){
        int c = w*32 + n*16 + lr;
        float s1  = g1[c] * rsqrtf(va1[c] + 1e-5f);
        float sh1 = be1[c] + (bp[c] - mu1[c]) * s1;
        #pragma unroll
        for (int m = 0; m < 4; ++m){
            #pragma unroll
            for (int r = 0; r < 4; ++r){
                int vx = m*16 + q*4 + r;
                float val = fmaxf(fmaf(acc[m][n][r], s1, sh1), 0.f);
                float vp  = __shfl_xor(val, 1);
                if ((lr & 1) == 0 && (val != 0.f || vp != 0.f)){
                    int pk = cellsPk[vx];
                    int P = pk >> 3, xp7 = pk & 7;
                    short* addr = dbf + (size_t)P*128 + (((c >> 3) ^ xp7) << 3) + (c & 7);
                    atomic_pk_add_bf16(addr, f2bf_s(val), f2bf_s(vp));
                }
            }
        }
    }
}

// ---------------- conv 3x3 + BN2 + ReLU + mask ----------------
// block: 2y x 64x x 128cout, 4 waves (yy,nn), wave tile 64pos x 64cout (m2n2),
// MFMA 32x32x16.  A: 4 padded rows, staged once (67.6 KB).  B: per-tap 32 KB
// LDS double-buffer shared by all waves (prefetch tap+1 while computing tap).
// Total LDS 133,120 B -> 1 block/CU; L2 traffic/block drops 644->356 KB.
__global__ void __launch_bounds__(256, 1)
kconv(const short* __restrict__ dbf, const short* __restrict__ wTs,
      const unsigned char* __restrict__ act, const float* __restrict__ cb,
      const float* __restrict__ g2, const float* __restrict__ be2,
      const float* __restrict__ mu2, const float* __restrict__ va2,
      float* __restrict__ out){
    __shared__ short Atile[4*1056*8];    // 67,584 B
    __shared__ short Bbuf[2][2048*8];    // 2 x 32,768 B
    const int t = threadIdx.x;
    // bijective XCD swizzle: 4096 blocks, 512/XCD
    const int bid = (blockIdx.x & 7)*512 + (blockIdx.x >> 3);
    const int b   = bid >> 11;
    const int rem = bid & 2047;
    const int y0  = (rem >> 3) << 1;
    const int x0  = (rem & 7) << 6;

    const int w   = t >> 6, l = t & 63;
    const int yy  = w >> 1, nn = w & 1;
    const int l31 = l & 31, hi = l >> 5;
    const int wbase16 = w*64*16;         // per-wave LDS chunk base (bytes) offset helper

    // ---- B-stage macro: tap TAP -> Bbuf[BUF] (2048 slots, 8/thread) ----
    #define STAGE_B(BUF, TAP) do {                                            \
        const short* gb = wTs + (size_t)(TAP)*16384;                          \
        _Pragma("unroll")                                                     \
        for (int j = 0; j < 8; ++j){                                          \
            int S = j*256 + t;                                                \
            __builtin_amdgcn_global_load_lds(                                 \
                (const __attribute__((address_space(1))) void*)(gb + S*8),    \
                (__attribute__((address_space(3))) void*)                    \
                    ((char*)Bbuf[BUF] + (size_t)(j*256*16) + wbase16), 16, 0, 0); \
        }                                                                     \
    } while(0)

    // prologue: B(0) + A (4 padded rows, 4224 slots)
    STAGE_B(0, 0);
    #pragma unroll
    for (int j = 0; j < 17; ++j){
        int S = j*256 + t;
        if (S < 4224){
            int r = S / 1056, s = S - r*1056;
            const short* gp = dbf + ((size_t)((b*514 + (y0 + r))*514 + x0)*16 + s)*8;
            __builtin_amdgcn_global_load_lds(
                (const __attribute__((address_space(1))) void*)gp,
                (__attribute__((address_space(3))) void*)
                    ((char*)Atile + (size_t)(j*256*16) + wbase16), 16, 0, 0);
        }
    }
    __syncthreads();

    f32x16 acc[2][2] = {};     // [mi][ni]
    const int bReadBase = (nn*64 + l31)*128;   // shorts; +ni*32*128
    const int bXor = l31 & 7;

    #pragma unroll
    for (int tap = 0; tap < 9; ++tap){
        if (tap < 8) STAGE_B((tap+1) & 1, tap+1);
        const short* Bc = Bbuf[tap & 1];
        const int ky = tap / 3, kx = tap - ky*3;
        const int row = yy + ky;
        const int p0 = l31 + kx, p1 = p0 + 32;
        const int base0 = (row*1056 + p0*16)*8;
        const int base1 = (row*1056 + p1*16)*8;
        const int pk7 = p0 & 7;
        #pragma unroll
        for (int kc = 0; kc < 8; ++kc){
            const int kslot = kc*2 + hi;
            const int q  = (kslot ^ pk7) << 3;
            const int qb = (kslot ^ bXor) << 3;
            bf16x8 a0 = *reinterpret_cast<const bf16x8*>(&Atile[base0 + q]);
            bf16x8 a1 = *reinterpret_cast<const bf16x8*>(&Atile[base1 + q]);
            bf16x8 b0 = *reinterpret_cast<const bf16x8*>(&Bc[bReadBase + qb]);
            bf16x8 b1 = *reinterpret_cast<const bf16x8*>(&Bc[bReadBase + 4096 + qb]);
            acc[0][0] = __builtin_amdgcn_mfma_f32_32x32x16_bf16(a0, b0, acc[0][0], 0, 0, 0);
            acc[0][1] = __builtin_amdgcn_mfma_f32_32x32x16_bf16(a0, b1, acc[0][1], 0, 0, 0);
            acc[1][0] = __builtin_amdgcn_mfma_f32_32x32x16_bf16(a1, b0, acc[1][0], 0, 0, 0);
            acc[1][1] = __builtin_amdgcn_mfma_f32_32x32x16_bf16(a1, b1, acc[1][1], 0, 0, 0);
        }
        __syncthreads();
    }
    #undef STAGE_B

    // epilogue: BN2 + ReLU + mask; D: col=l31 (cout), row=(r&3)+8*(r>>2)+4*hi
    const int yg = y0 + yy;
    const size_t rowcell = (size_t)(b*Yq + yg)*Xq + x0;
    #pragma unroll
    for (int ni = 0; ni < 2; ++ni){
        int c = nn*64 + ni*32 + l31;
        float s2  = g2[c] * rsqrtf(va2[c] + 1e-3f);
        float sh2 = be2[c] + (cb[c] - mu2[c]) * s2;
        #pragma unroll
        for (int mi = 0; mi < 2; ++mi){
            #pragma unroll
            for (int r = 0; r < 16; ++r){
                int pos = mi*32 + (r & 3) + ((r >> 2) << 3) + hi*4;
                size_t cell = rowcell + pos;
                float v = act[cell] ? fmaxf(fmaf(acc[mi][ni][r], s2, sh2), 0.f) : 0.f;
                out[cell*128 + c] = v;
            }
        }
    }
}

extern "C" void kernel_launch(void* const* d_in, const int* in_sizes, int n_in,
                              void* d_out, int out_size, void* d_ws, size_t ws_size,
                              hipStream_t stream){
    const float* vf  = (const float*)d_in[0];
    const int*   vc  = (const int*)  d_in[1];
    const float* Wp  = (const float*)d_in[2];
    const float* bp  = (const float*)d_in[3];
    const float* g1  = (const float*)d_in[4];
    const float* be1 = (const float*)d_in[5];
    const float* mu1 = (const float*)d_in[6];
    const float* va1 = (const float*)d_in[7];
    const float* cw  = (const float*)d_in[8];
    const float* cb  = (const float*)d_in[9];
    const float* g2  = (const float*)d_in[10];
    const float* be2 = (const float*)d_in[11];
    const float* mu2 = (const float*)d_in[12];
    const float* va2 = (const float*)d_in[13];
    float* out = (float*)d_out;
    char* ws = (char*)d_ws;

    // ws layout (bytes):
    //   dbf bf16 [2][514][514][128] : 135,268,352 @ 0   (padded, pre-swizzled)
    //   act  u8  [2][512][512]      :     524,288 @ 135,268,352
    //   wTs  bf16 [9][128][128]     :     294,912 @ 135,792,640  (pre-swizzled)
    //   wpT  bf16 [128][192]        :      49,152 @ 136,087,552  (end 136,136,704)
    if (ws_size < 136136704ull) return;
    short* dbf = (short*)ws;
    unsigned char* act = (unsigned char*)(ws + 135268352);
    short* wTs = (short*)(ws + 135792640);
    short* wpT = (short*)(ws + 136087552);

    hipMemsetAsync(dbf, 0, 135268352, stream);
    hipMemsetAsync(act, 0, 524288, stream);
    kprep<<<672, 256, 0, stream>>>(cw, Wp, wTs, wpT);
    kproj<<<6250, 256, 0, stream>>>(vf, vc, wpT, bp, g1, be1, mu1, va1, dbf, act);
    kconv<<<4096, 256, 0, stream>>>(dbf, wTs, act, cb, g2, be2, mu2, va2, out);
}

// Round 6
// 426.531 us; speedup vs baseline: 1.5365x; 1.0099x over previous
//
#include <hip/hip_runtime.h>

#define Bq 2
#define Yq 512
#define Xq 512

typedef __bf16 bf16x8 __attribute__((ext_vector_type(8)));
typedef float f32x4 __attribute__((ext_vector_type(4)));
typedef float f32x16 __attribute__((ext_vector_type(16)));
typedef short s16x8 __attribute__((ext_vector_type(8)));
typedef short s16x2 __attribute__((ext_vector_type(2)));

__device__ __forceinline__ short f2bf_s(float f){
    return __builtin_bit_cast(short, static_cast<__bf16>(f));
}
__device__ __forceinline__ float bfbits2f(unsigned short u){
    unsigned v = ((unsigned)u) << 16; return __builtin_bit_cast(float, v);
}

__device__ __forceinline__ void atomic_pk_add_bf16(short* addr, short lo, short hi){
#if __has_builtin(__builtin_amdgcn_global_atomic_fadd_v2bf16)
    s16x2 v; v[0] = lo; v[1] = hi;
    __builtin_amdgcn_global_atomic_fadd_v2bf16(
        (__attribute__((address_space(1))) s16x2*)addr, v);
#else
    unsigned* p = (unsigned*)addr;
    float flo = bfbits2f((unsigned short)lo), fhi = bfbits2f((unsigned short)hi);
    unsigned old = *p, seen;
    do {
        seen = old;
        unsigned short olo = (unsigned short)(seen & 0xffff);
        unsigned short ohi = (unsigned short)(seen >> 16);
        unsigned short nlo = (unsigned short)f2bf_s(bfbits2f(olo) + flo);
        unsigned short nhi = (unsigned short)f2bf_s(bfbits2f(ohi) + fhi);
        unsigned nv = ((unsigned)nhi << 16) | nlo;
        old = atomicCAS(p, seen, nv);
    } while (old != seen);
#endif
}

// ---------------- weight transpose + bf16 convert ----------------
// wTs[tap][cout][slot]: PRE-SWIZZLED for LDS — cin-group g of cout stored at
// slot (g&8) | ((g&7) ^ (cout&7)); linear global_load_lds then gives
// conflict-free ds_read_b128 in kconv.
// wpT[cout][cin] <- W_proj[cin][cout]
__global__ void kprep(const float* __restrict__ conv_w, const float* __restrict__ W_proj,
                      short* __restrict__ wTs, short* __restrict__ wpT){
    int tid = blockIdx.x*256 + threadIdx.x;
    if (tid < 9*128*128){
        int tap = tid >> 14; int r = tid & 16383; int co = r >> 7; int ci = r & 127;
        int g = ci >> 3, e = ci & 7;
        wTs[tap*16384 + co*128 + (((g & 8) | ((g & 7) ^ (co & 7))) << 3) + e] =
            f2bf_s(conv_w[tap*16384 + ci*128 + co]);
    }
    int e = tid - 9*128*128;
    if (e >= 0 && e < 128*192){
        int co = e / 192; int ci = e - co*192;
        wpT[e] = f2bf_s(W_proj[ci*128 + co]);
    }
}

// ---------------- projection + BN1 + ReLU + bf16 pk-atomic scatter ----------
__global__ void __launch_bounds__(256, 2)
kproj(const float* __restrict__ vf, const int* __restrict__ vc,
      const short* __restrict__ wpT, const float* __restrict__ bp,
      const float* __restrict__ g1, const float* __restrict__ be1,
      const float* __restrict__ mu1, const float* __restrict__ va1,
      short* __restrict__ dbf, unsigned char* __restrict__ act){
    __shared__ short A[64*200];
    __shared__ int cellsPk[64];     // P*8 + (xp&7)
    const int t = threadIdx.x;
    const int v0 = blockIdx.x * 64;

    const float4* vf4 = reinterpret_cast<const float4*>(vf);
    #pragma unroll
    for (int j = 0; j < 12; ++j){
        int i = t + j*256;
        int v = i / 48, kq = i - v*48;
        float4 x = vf4[(size_t)(v0 + v)*48 + kq];
        short4 s; s.x=f2bf_s(x.x); s.y=f2bf_s(x.y); s.z=f2bf_s(x.z); s.w=f2bf_s(x.w);
        *reinterpret_cast<short4*>(&A[v*200 + kq*4]) = s;
    }
    if (t < 64){
        int vi = v0 + t;
        int bi = vc[vi*4 + 0], yi = vc[vi*4 + 2], xi = vc[vi*4 + 3];
        act[(bi*Yq + yi)*Xq + xi] = 1;
        int P = (bi*514 + (yi + 1))*514 + (xi + 1);
        cellsPk[t] = P*8 + ((xi + 1) & 7);
    }
    __syncthreads();

    const int w  = t >> 6;
    const int l  = t & 63;
    const int lr = l & 15;
    const int q  = l >> 4;

    const short* wp_lane = wpT + (size_t)(w*32 + lr)*192 + q*8;
    bf16x8 bb[2][6];
    #pragma unroll
    for (int n = 0; n < 2; ++n)
        #pragma unroll
        for (int kc = 0; kc < 6; ++kc)
            bb[n][kc] = *reinterpret_cast<const bf16x8*>(wp_lane + n*16*192 + kc*32);

    f32x4 acc[4][2] = {};
    #pragma unroll
    for (int kc = 0; kc < 6; ++kc){
        bf16x8 a[4];
        #pragma unroll
        for (int m = 0; m < 4; ++m)
            a[m] = *reinterpret_cast<const bf16x8*>(&A[(m*16 + lr)*200 + kc*32 + q*8]);
        #pragma unroll
        for (int m = 0; m < 4; ++m)
            #pragma unroll
            for (int n = 0; n < 2; ++n)
                acc[m][n] = __builtin_amdgcn_mfma_f32_16x16x32_bf16(a[m], bb[n][kc], acc[m][n], 0, 0, 0);
    }

    #pragma unroll
    for (int n = 0; n < 2; ++n){
        int c = w*32 + n*16 + lr;
        float s1  = g1[c] * rsqrtf(va1[c] + 1e-5f);
        float sh1 = be1[c] + (bp[c] - mu1[c]) * s1;
        #pragma unroll
        for (int m = 0; m < 4; ++m){
            #pragma unroll
            for (int r = 0; r < 4; ++r){
                int vx = m*16 + q*4 + r;
                float val = fmaxf(fmaf(acc[m][n][r], s1, sh1), 0.f);
                float vp  = __shfl_xor(val, 1);
                if ((lr & 1) == 0 && (val != 0.f || vp != 0.f)){
                    int pk = cellsPk[vx];
                    int P = pk >> 3, xp7 = pk & 7;
                    short* addr = dbf + (size_t)P*128 + (((c >> 3) ^ xp7) << 3) + (c & 7);
                    atomic_pk_add_bf16(addr, f2bf_s(val), f2bf_s(vp));
                }
            }
        }
    }
}

// ---------------- conv 3x3 + BN2 + ReLU + mask ----------------
// block: 4y x 64x x 128cout, 512 threads / 8 waves (yy in 0..3, nn in 0..1),
// wave tile 64pos x 64cout (m2n2), MFMA 32x32x16.
// A: 6 padded rows staged once (101,376 B).  B: HALF-TAP (16 KB) ping-pong
// LDS buffers, 18 phases: {issue stage(h+1); compute h; barrier}.
// LDS 134,144 B -> 1 block/CU, 8 waves (2/SIMD).
__global__ void __launch_bounds__(512, 2)
kconv(const short* __restrict__ dbf, const short* __restrict__ wTs,
      const unsigned char* __restrict__ act, const float* __restrict__ cb,
      const float* __restrict__ g2, const float* __restrict__ be2,
      const float* __restrict__ mu2, const float* __restrict__ va2,
      float* __restrict__ out){
    __shared__ short Atile[6*1056*8];    // 101,376 B
    __shared__ short Bbuf[2][1024*8];    // 2 x 16,384 B
    const int t = threadIdx.x;
    // bijective XCD swizzle: 2048 blocks, 256/XCD
    const int bid = (blockIdx.x & 7)*256 + (blockIdx.x >> 3);
    const int b   = bid >> 10;
    const int rem = bid & 1023;
    const int y0  = (rem >> 3) << 2;   // 4 output rows y0..y0+3
    const int x0  = (rem & 7) << 6;

    const int w   = t >> 6, l = t & 63;
    const int yy  = w >> 1, nn = w & 1;
    const int l31 = l & 31, hi = l >> 5;
    const int wbase16 = w*64*16;       // wave-uniform LDS chunk base (bytes)

    // ---- stage half-tap H -> Bbuf[BUF]: 1024 16B-slots, 2/thread ----
    // slot S = co*8 + s'  <-  wTs[tap][co][ (H&1)*8 + s' ]
    #define STAGE_B(BUF, H) do {                                              \
        const short* gb = wTs + (size_t)((H) >> 1)*16384 + ((H) & 1)*64;      \
        _Pragma("unroll")                                                     \
        for (int j = 0; j < 2; ++j){                                          \
            int S = j*512 + t;                                                \
            const short* gp = gb + (S >> 3)*128 + (S & 7)*8;                  \
            __builtin_amdgcn_global_load_lds(                                 \
                (const __attribute__((address_space(1))) void*)gp,            \
                (__attribute__((address_space(3))) void*)                    \
                    ((char*)Bbuf[BUF] + (size_t)(j*512*16) + wbase16), 16, 0, 0); \
        }                                                                     \
    } while(0)

    // prologue: B half-tap 0 + A (6 padded rows, 6336 slots; 6336 = 99 waves)
    STAGE_B(0, 0);
    #pragma unroll
    for (int j = 0; j < 13; ++j){
        int S = j*512 + t;
        if (S < 6336){
            int r = S / 1056, s = S - r*1056;
            const short* gp = dbf + ((size_t)((b*514 + (y0 + r))*514 + x0)*16 + s)*8;
            __builtin_amdgcn_global_load_lds(
                (const __attribute__((address_space(1))) void*)gp,
                (__attribute__((address_space(3))) void*)
                    ((char*)Atile + (size_t)(j*512*16) + wbase16), 16, 0, 0);
        }
    }
    __syncthreads();

    f32x16 acc[2][2] = {};               // [mi][ni]
    const int bReadBase = (nn*64 + l31)*64;   // shorts; +ni*2048
    const int bXor = l31 & 7;

    #pragma unroll
    for (int h = 0; h < 18; ++h){
        if (h < 17) STAGE_B((h+1) & 1, h+1);
        const short* Bc = Bbuf[h & 1];
        const int tap = h >> 1, hh = h & 1;
        const int ky = tap / 3, kx = tap - ky*3;
        const int row = yy + ky;
        const int p0 = l31 + kx, p1 = p0 + 32;
        const int base0 = (row*1056 + p0*16)*8;
        const int base1 = (row*1056 + p1*16)*8;
        const int pk7 = p0 & 7;
        #pragma unroll
        for (int kc = 0; kc < 4; ++kc){
            const int ks  = kc*2 + hi;           // local k-slot 0..7
            const int q   = ((hh*8 + ks) ^ pk7) << 3;
            const int qb  = (ks ^ bXor) << 3;
            bf16x8 a0 = *reinterpret_cast<const bf16x8*>(&Atile[base0 + q]);
            bf16x8 a1 = *reinterpret_cast<const bf16x8*>(&Atile[base1 + q]);
            bf16x8 b0 = *reinterpret_cast<const bf16x8*>(&Bc[bReadBase + qb]);
            bf16x8 b1 = *reinterpret_cast<const bf16x8*>(&Bc[bReadBase + 2048 + qb]);
            acc[0][0] = __builtin_amdgcn_mfma_f32_32x32x16_bf16(a0, b0, acc[0][0], 0, 0, 0);
            acc[0][1] = __builtin_amdgcn_mfma_f32_32x32x16_bf16(a0, b1, acc[0][1], 0, 0, 0);
            acc[1][0] = __builtin_amdgcn_mfma_f32_32x32x16_bf16(a1, b0, acc[1][0], 0, 0, 0);
            acc[1][1] = __builtin_amdgcn_mfma_f32_32x32x16_bf16(a1, b1, acc[1][1], 0, 0, 0);
        }
        __syncthreads();
    }
    #undef STAGE_B

    // epilogue: BN2 + ReLU + mask; D: col=l31 (cout), row=(r&3)+8*(r>>2)+4*hi
    const int yg = y0 + yy;
    const size_t rowcell = (size_t)(b*Yq + yg)*Xq + x0;
    #pragma unroll
    for (int ni = 0; ni < 2; ++ni){
        int c = nn*64 + ni*32 + l31;
        float s2  = g2[c] * rsqrtf(va2[c] + 1e-3f);
        float sh2 = be2[c] + (cb[c] - mu2[c]) * s2;
        #pragma unroll
        for (int mi = 0; mi < 2; ++mi){
            #pragma unroll
            for (int r = 0; r < 16; ++r){
                int pos = mi*32 + (r & 3) + ((r >> 2) << 3) + hi*4;
                size_t cell = rowcell + pos;
                float v = act[cell] ? fmaxf(fmaf(acc[mi][ni][r], s2, sh2), 0.f) : 0.f;
                out[cell*128 + c] = v;
            }
        }
    }
}

extern "C" void kernel_launch(void* const* d_in, const int* in_sizes, int n_in,
                              void* d_out, int out_size, void* d_ws, size_t ws_size,
                              hipStream_t stream){
    const float* vf  = (const float*)d_in[0];
    const int*   vc  = (const int*)  d_in[1];
    const float* Wp  = (const float*)d_in[2];
    const float* bp  = (const float*)d_in[3];
    const float* g1  = (const float*)d_in[4];
    const float* be1 = (const float*)d_in[5];
    const float* mu1 = (const float*)d_in[6];
    const float* va1 = (const float*)d_in[7];
    const float* cw  = (const float*)d_in[8];
    const float* cb  = (const float*)d_in[9];
    const float* g2  = (const float*)d_in[10];
    const float* be2 = (const float*)d_in[11];
    const float* mu2 = (const float*)d_in[12];
    const float* va2 = (const float*)d_in[13];
    float* out = (float*)d_out;
    char* ws = (char*)d_ws;

    // ws layout (bytes):
    //   dbf bf16 [2][514][514][128] : 135,268,352 @ 0   (padded, pre-swizzled)
    //   act  u8  [2][512][512]      :     524,288 @ 135,268,352
    //   wTs  bf16 [9][128][128]     :     294,912 @ 135,792,640  (pre-swizzled)
    //   wpT  bf16 [128][192]        :      49,152 @ 136,087,552  (end 136,136,704)
    if (ws_size < 136136704ull) return;
    short* dbf = (short*)ws;
    unsigned char* act = (unsigned char*)(ws + 135268352);
    short* wTs = (short*)(ws + 135792640);
    short* wpT = (short*)(ws + 136087552);

    hipMemsetAsync(dbf, 0, 135268352, stream);
    hipMemsetAsync(act, 0, 524288, stream);
    kprep<<<672, 256, 0, stream>>>(cw, Wp, wTs, wpT);
    kproj<<<6250, 256, 0, stream>>>(vf, vc, wpT, bp, g1, be1, mu1, va1, dbf, act);
    kconv<<<2048, 512, 0, stream>>>(dbf, wTs, act, cb, g2, be2, mu2, va2, out);
}

// Round 7
// 402.702 us; speedup vs baseline: 1.6274x; 1.0592x over previous
//
#include <hip/hip_runtime.h>

#define Bq 2
#define Yq 512
#define Xq 512
#define NVOX 400000

typedef __bf16 bf16x8 __attribute__((ext_vector_type(8)));
typedef float f32x4 __attribute__((ext_vector_type(4)));
typedef float f32x16 __attribute__((ext_vector_type(16)));
typedef short s16x8 __attribute__((ext_vector_type(8)));
typedef short s16x2 __attribute__((ext_vector_type(2)));

__device__ __forceinline__ short f2bf_s(float f){
    return __builtin_bit_cast(short, static_cast<__bf16>(f));
}

__device__ __forceinline__ void atomic_pk_add_bf16(short* addr, unsigned data){
#if __has_builtin(__builtin_amdgcn_global_atomic_fadd_v2bf16)
    s16x2 v; v[0] = (short)(data & 0xffff); v[1] = (short)(data >> 16);
    __builtin_amdgcn_global_atomic_fadd_v2bf16(
        (__attribute__((address_space(1))) s16x2*)addr, v);
#else
    asm volatile("global_atomic_pk_add_bf16 %0, %1, off"
                 :: "v"(addr), "v"(data) : "memory");
#endif
}

// ---------------- weight transpose + bf16 convert ----------------
// wTs[tap][cout][slot]: PRE-SWIZZLED for LDS — cin-group g of cout stored at
// slot (g&8) | ((g&7) ^ (cout&7)); linear global_load_lds then gives
// conflict-free ds_read_b128 in kconv.
// wpT[cout][cin] <- W_proj[cin][cout]
__global__ void kprep(const float* __restrict__ conv_w, const float* __restrict__ W_proj,
                      short* __restrict__ wTs, short* __restrict__ wpT){
    int tid = blockIdx.x*256 + threadIdx.x;
    if (tid < 9*128*128){
        int tap = tid >> 14; int r = tid & 16383; int co = r >> 7; int ci = r & 127;
        int g = ci >> 3, e = ci & 7;
        wTs[tap*16384 + co*128 + (((g & 8) | ((g & 7) ^ (co & 7))) << 3) + e] =
            f2bf_s(conv_w[tap*16384 + ci*128 + co]);
    }
    int e = tid - 9*128*128;
    if (e >= 0 && e < 128*192){
        int co = e / 192; int ci = e - co*192;
        wpT[e] = f2bf_s(W_proj[ci*128 + co]);
    }
}

// ---------------- per-cell multiplicity count + active mask ----------------
__global__ void kcount(const int* __restrict__ vc, unsigned* __restrict__ cnt,
                       unsigned char* __restrict__ act){
    int i = blockIdx.x*256 + threadIdx.x;
    if (i >= NVOX) return;
    const int4 c = *reinterpret_cast<const int4*>(vc + i*4);
    int cell = (c.x*Yq + c.z)*Xq + c.w;
    act[cell] = 1;
    atomicAdd(&cnt[cell], 1u);
}

// ---------------- projection + BN1 + ReLU + scatter ----------
// Singleton cells (cnt==1, ~47%): plain 4B store.  Multi cells: pk-atomic.
__global__ void __launch_bounds__(256, 2)
kproj(const float* __restrict__ vf, const int* __restrict__ vc,
      const unsigned* __restrict__ cnt,
      const short* __restrict__ wpT, const float* __restrict__ bp,
      const float* __restrict__ g1, const float* __restrict__ be1,
      const float* __restrict__ mu1, const float* __restrict__ va1,
      short* __restrict__ dbf){
    __shared__ short A[64*200];
    __shared__ int cellsPk[64];     // (multi<<30) | P*8 + (xp&7)
    const int t = threadIdx.x;
    const int v0 = blockIdx.x * 64;

    const float4* vf4 = reinterpret_cast<const float4*>(vf);
    #pragma unroll
    for (int j = 0; j < 12; ++j){
        int i = t + j*256;
        int v = i / 48, kq = i - v*48;
        float4 x = vf4[(size_t)(v0 + v)*48 + kq];
        short4 s; s.x=f2bf_s(x.x); s.y=f2bf_s(x.y); s.z=f2bf_s(x.z); s.w=f2bf_s(x.w);
        *reinterpret_cast<short4*>(&A[v*200 + kq*4]) = s;
    }
    if (t < 64){
        int vi = v0 + t;
        int bi = vc[vi*4 + 0], yi = vc[vi*4 + 2], xi = vc[vi*4 + 3];
        unsigned cn = cnt[(bi*Yq + yi)*Xq + xi];
        int P = (bi*514 + (yi + 1))*514 + (xi + 1);
        cellsPk[t] = (P*8 + ((xi + 1) & 7)) | ((cn > 1) ? (1 << 30) : 0);
    }
    __syncthreads();

    const int w  = t >> 6;
    const int l  = t & 63;
    const int lr = l & 15;
    const int q  = l >> 4;

    const short* wp_lane = wpT + (size_t)(w*32 + lr)*192 + q*8;
    bf16x8 bb[2][6];
    #pragma unroll
    for (int n = 0; n < 2; ++n)
        #pragma unroll
        for (int kc = 0; kc < 6; ++kc)
            bb[n][kc] = *reinterpret_cast<const bf16x8*>(wp_lane + n*16*192 + kc*32);

    f32x4 acc[4][2] = {};
    #pragma unroll
    for (int kc = 0; kc < 6; ++kc){
        bf16x8 a[4];
        #pragma unroll
        for (int m = 0; m < 4; ++m)
            a[m] = *reinterpret_cast<const bf16x8*>(&A[(m*16 + lr)*200 + kc*32 + q*8]);
        #pragma unroll
        for (int m = 0; m < 4; ++m)
            #pragma unroll
            for (int n = 0; n < 2; ++n)
                acc[m][n] = __builtin_amdgcn_mfma_f32_16x16x32_bf16(a[m], bb[n][kc], acc[m][n], 0, 0, 0);
    }

    #pragma unroll
    for (int n = 0; n < 2; ++n){
        int c = w*32 + n*16 + lr;
        float s1  = g1[c] * rsqrtf(va1[c] + 1e-5f);
        float sh1 = be1[c] + (bp[c] - mu1[c]) * s1;
        #pragma unroll
        for (int m = 0; m < 4; ++m){
            #pragma unroll
            for (int r = 0; r < 4; ++r){
                int vx = m*16 + q*4 + r;
                float val = fmaxf(fmaf(acc[m][n][r], s1, sh1), 0.f);
                float vp  = __shfl_xor(val, 1);
                if ((lr & 1) == 0){
                    int pk = cellsPk[vx];
                    int multi = pk >> 30;
                    int P = (pk & 0x3fffffff) >> 3, xp7 = pk & 7;
                    short* addr = dbf + (size_t)P*128 + (((c >> 3) ^ xp7) << 3) + (c & 7);
                    unsigned data = (unsigned)(unsigned short)f2bf_s(val)
                                  | ((unsigned)(unsigned short)f2bf_s(vp) << 16);
                    if (!multi){
                        if (data) *reinterpret_cast<unsigned*>(addr) = data;
                    } else {
                        if (data) atomic_pk_add_bf16(addr, data);
                    }
                }
            }
        }
    }
}

// ---------------- conv 3x3 + BN2 + ReLU + mask (unchanged from R6) --------
__global__ void __launch_bounds__(512, 2)
kconv(const short* __restrict__ dbf, const short* __restrict__ wTs,
      const unsigned char* __restrict__ act, const float* __restrict__ cb,
      const float* __restrict__ g2, const float* __restrict__ be2,
      const float* __restrict__ mu2, const float* __restrict__ va2,
      float* __restrict__ out){
    __shared__ short Atile[6*1056*8];    // 101,376 B
    __shared__ short Bbuf[2][1024*8];    // 2 x 16,384 B
    const int t = threadIdx.x;
    const int bid = (blockIdx.x & 7)*256 + (blockIdx.x >> 3);
    const int b   = bid >> 10;
    const int rem = bid & 1023;
    const int y0  = (rem >> 3) << 2;
    const int x0  = (rem & 7) << 6;

    const int w   = t >> 6, l = t & 63;
    const int yy  = w >> 1, nn = w & 1;
    const int l31 = l & 31, hi = l >> 5;
    const int wbase16 = w*64*16;

    #define STAGE_B(BUF, H) do {                                              \
        const short* gb = wTs + (size_t)((H) >> 1)*16384 + ((H) & 1)*64;      \
        _Pragma("unroll")                                                     \
        for (int j = 0; j < 2; ++j){                                          \
            int S = j*512 + t;                                                \
            const short* gp = gb + (S >> 3)*128 + (S & 7)*8;                  \
            __builtin_amdgcn_global_load_lds(                                 \
                (const __attribute__((address_space(1))) void*)gp,            \
                (__attribute__((address_space(3))) void*)                    \
                    ((char*)Bbuf[BUF] + (size_t)(j*512*16) + wbase16), 16, 0, 0); \
        }                                                                     \
    } while(0)

    STAGE_B(0, 0);
    #pragma unroll
    for (int j = 0; j < 13; ++j){
        int S = j*512 + t;
        if (S < 6336){
            int r = S / 1056, s = S - r*1056;
            const short* gp = dbf + ((size_t)((b*514 + (y0 + r))*514 + x0)*16 + s)*8;
            __builtin_amdgcn_global_load_lds(
                (const __attribute__((address_space(1))) void*)gp,
                (__attribute__((address_space(3))) void*)
                    ((char*)Atile + (size_t)(j*512*16) + wbase16), 16, 0, 0);
        }
    }
    __syncthreads();

    f32x16 acc[2][2] = {};
    const int bReadBase = (nn*64 + l31)*64;
    const int bXor = l31 & 7;

    #pragma unroll
    for (int h = 0; h < 18; ++h){
        if (h < 17) STAGE_B((h+1) & 1, h+1);
        const short* Bc = Bbuf[h & 1];
        const int tap = h >> 1, hh = h & 1;
        const int ky = tap / 3, kx = tap - ky*3;
        const int row = yy + ky;
        const int p0 = l31 + kx, p1 = p0 + 32;
        const int base0 = (row*1056 + p0*16)*8;
        const int base1 = (row*1056 + p1*16)*8;
        const int pk7 = p0 & 7;
        #pragma unroll
        for (int kc = 0; kc < 4; ++kc){
            const int ks  = kc*2 + hi;
            const int q   = ((hh*8 + ks) ^ pk7) << 3;
            const int qb  = (ks ^ bXor) << 3;
            bf16x8 a0 = *reinterpret_cast<const bf16x8*>(&Atile[base0 + q]);
            bf16x8 a1 = *reinterpret_cast<const bf16x8*>(&Atile[base1 + q]);
            bf16x8 b0 = *reinterpret_cast<const bf16x8*>(&Bc[bReadBase + qb]);
            bf16x8 b1 = *reinterpret_cast<const bf16x8*>(&Bc[bReadBase + 2048 + qb]);
            acc[0][0] = __builtin_amdgcn_mfma_f32_32x32x16_bf16(a0, b0, acc[0][0], 0, 0, 0);
            acc[0][1] = __builtin_amdgcn_mfma_f32_32x32x16_bf16(a0, b1, acc[0][1], 0, 0, 0);
            acc[1][0] = __builtin_amdgcn_mfma_f32_32x32x16_bf16(a1, b0, acc[1][0], 0, 0, 0);
            acc[1][1] = __builtin_amdgcn_mfma_f32_32x32x16_bf16(a1, b1, acc[1][1], 0, 0, 0);
        }
        __syncthreads();
    }
    #undef STAGE_B

    const int yg = y0 + yy;
    const size_t rowcell = (size_t)(b*Yq + yg)*Xq + x0;
    #pragma unroll
    for (int ni = 0; ni < 2; ++ni){
        int c = nn*64 + ni*32 + l31;
        float s2  = g2[c] * rsqrtf(va2[c] + 1e-3f);
        float sh2 = be2[c] + (cb[c] - mu2[c]) * s2;
        #pragma unroll
        for (int mi = 0; mi < 2; ++mi){
            #pragma unroll
            for (int r = 0; r < 16; ++r){
                int pos = mi*32 + (r & 3) + ((r >> 2) << 3) + hi*4;
                size_t cell = rowcell + pos;
                float v = act[cell] ? fmaxf(fmaf(acc[mi][ni][r], s2, sh2), 0.f) : 0.f;
                out[cell*128 + c] = v;
            }
        }
    }
}

extern "C" void kernel_launch(void* const* d_in, const int* in_sizes, int n_in,
                              void* d_out, int out_size, void* d_ws, size_t ws_size,
                              hipStream_t stream){
    const float* vf  = (const float*)d_in[0];
    const int*   vc  = (const int*)  d_in[1];
    const float* Wp  = (const float*)d_in[2];
    const float* bp  = (const float*)d_in[3];
    const float* g1  = (const float*)d_in[4];
    const float* be1 = (const float*)d_in[5];
    const float* mu1 = (const float*)d_in[6];
    const float* va1 = (const float*)d_in[7];
    const float* cw  = (const float*)d_in[8];
    const float* cb  = (const float*)d_in[9];
    const float* g2  = (const float*)d_in[10];
    const float* be2 = (const float*)d_in[11];
    const float* mu2 = (const float*)d_in[12];
    const float* va2 = (const float*)d_in[13];
    float* out = (float*)d_out;
    char* ws = (char*)d_ws;

    // ws layout (bytes):
    //   dbf bf16 [2][514][514][128] : 135,268,352 @ 0   (padded, pre-swizzled)
    //   act  u8  [2][512][512]      :     524,288 @ 135,268,352
    //   wTs  bf16 [9][128][128]     :     294,912 @ 135,792,640  (pre-swizzled)
    //   wpT  bf16 [128][192]        :      49,152 @ 136,087,552
    //   cnt  u32 [2][512][512]      :   2,097,152 @ 136,136,704  (end 138,233,856)
    if (ws_size < 138233856ull) return;
    short* dbf = (short*)ws;
    unsigned char* act = (unsigned char*)(ws + 135268352);
    short* wTs = (short*)(ws + 135792640);
    short* wpT = (short*)(ws + 136087552);
    unsigned* cnt = (unsigned*)(ws + 136136704);

    hipMemsetAsync(dbf, 0, 135268352, stream);
    hipMemsetAsync(act, 0, 524288, stream);
    hipMemsetAsync(cnt, 0, 2097152, stream);
    kprep<<<672, 256, 0, stream>>>(cw, Wp, wTs, wpT);
    kcount<<<1563, 256, 0, stream>>>(vc, cnt, act);
    kproj<<<6250, 256, 0, stream>>>(vf, vc, cnt, wpT, bp, g1, be1, mu1, va1, dbf);
    kconv<<<2048, 512, 0, stream>>>(dbf, wTs, act, cb, g2, be2, mu2, va2, out);
}

// Round 8
// 390.561 us; speedup vs baseline: 1.6780x; 1.0311x over previous
//
#include <hip/hip_runtime.h>

#define Bq 2
#define Yq 512
#define Xq 512
#define NVOX 400000

typedef __bf16 bf16x8 __attribute__((ext_vector_type(8)));
typedef float f32x4 __attribute__((ext_vector_type(4)));
typedef float f32x16 __attribute__((ext_vector_type(16)));
typedef short s16x8 __attribute__((ext_vector_type(8)));
typedef short s16x2 __attribute__((ext_vector_type(2)));

__device__ __forceinline__ short f2bf_s(float f){
    return __builtin_bit_cast(short, static_cast<__bf16>(f));
}

__device__ __forceinline__ void atomic_pk_add_bf16(short* addr, unsigned data){
#if __has_builtin(__builtin_amdgcn_global_atomic_fadd_v2bf16)
    s16x2 v; v[0] = (short)(data & 0xffff); v[1] = (short)(data >> 16);
    __builtin_amdgcn_global_atomic_fadd_v2bf16(
        (__attribute__((address_space(1))) s16x2*)addr, v);
#else
    asm volatile("global_atomic_pk_add_bf16 %0, %1, off"
                 :: "v"(addr), "v"(data) : "memory");
#endif
}

// ---------------- weight transpose + bf16 convert ----------------
// wTs[tap][cout][slot]: PRE-SWIZZLED for LDS — cin-group g of cout stored at
// slot (g&8) | ((g&7) ^ (cout&7)); linear global_load_lds then gives
// conflict-free ds_read_b128 in kconv.
// wpT[cout][cin] <- W_proj[cin][cout]
__global__ void kprep(const float* __restrict__ conv_w, const float* __restrict__ W_proj,
                      short* __restrict__ wTs, short* __restrict__ wpT){
    int tid = blockIdx.x*256 + threadIdx.x;
    if (tid < 9*128*128){
        int tap = tid >> 14; int r = tid & 16383; int co = r >> 7; int ci = r & 127;
        int g = ci >> 3, e = ci & 7;
        wTs[tap*16384 + co*128 + (((g & 8) | ((g & 7) ^ (co & 7))) << 3) + e] =
            f2bf_s(conv_w[tap*16384 + ci*128 + co]);
    }
    int e = tid - 9*128*128;
    if (e >= 0 && e < 128*192){
        int co = e / 192; int ci = e - co*192;
        wpT[e] = f2bf_s(W_proj[ci*128 + co]);
    }
}

// ---------------- per-cell multiplicity count + active mask ----------------
__global__ void kcount(const int* __restrict__ vc, unsigned* __restrict__ cnt,
                       unsigned char* __restrict__ act){
    int i = blockIdx.x*256 + threadIdx.x;
    if (i >= NVOX) return;
    const int4 c = *reinterpret_cast<const int4*>(vc + i*4);
    int cell = (c.x*Yq + c.z)*Xq + c.w;
    act[cell] = 1;
    atomicAdd(&cnt[cell], 1u);
}

// ---------------- projection + BN1 + ReLU + scatter ----------
// Singleton cells (cnt==1, ~47%): plain 4B store.  Multi cells: pk-atomic.
__global__ void __launch_bounds__(256, 2)
kproj(const float* __restrict__ vf, const int* __restrict__ vc,
      const unsigned* __restrict__ cnt,
      const short* __restrict__ wpT, const float* __restrict__ bp,
      const float* __restrict__ g1, const float* __restrict__ be1,
      const float* __restrict__ mu1, const float* __restrict__ va1,
      short* __restrict__ dbf){
    __shared__ short A[64*200];
    __shared__ int cellsPk[64];     // (multi<<30) | P*8 + (xp&7)
    const int t = threadIdx.x;
    const int v0 = blockIdx.x * 64;

    const float4* vf4 = reinterpret_cast<const float4*>(vf);
    #pragma unroll
    for (int j = 0; j < 12; ++j){
        int i = t + j*256;
        int v = i / 48, kq = i - v*48;
        float4 x = vf4[(size_t)(v0 + v)*48 + kq];
        short4 s; s.x=f2bf_s(x.x); s.y=f2bf_s(x.y); s.z=f2bf_s(x.z); s.w=f2bf_s(x.w);
        *reinterpret_cast<short4*>(&A[v*200 + kq*4]) = s;
    }
    if (t < 64){
        int vi = v0 + t;
        int bi = vc[vi*4 + 0], yi = vc[vi*4 + 2], xi = vc[vi*4 + 3];
        unsigned cn = cnt[(bi*Yq + yi)*Xq + xi];
        int P = (bi*514 + (yi + 1))*514 + (xi + 1);
        cellsPk[t] = (P*8 + ((xi + 1) & 7)) | ((cn > 1) ? (1 << 30) : 0);
    }
    __syncthreads();

    const int w  = t >> 6;
    const int l  = t & 63;
    const int lr = l & 15;
    const int q  = l >> 4;

    const short* wp_lane = wpT + (size_t)(w*32 + lr)*192 + q*8;
    bf16x8 bb[2][6];
    #pragma unroll
    for (int n = 0; n < 2; ++n)
        #pragma unroll
        for (int kc = 0; kc < 6; ++kc)
            bb[n][kc] = *reinterpret_cast<const bf16x8*>(wp_lane + n*16*192 + kc*32);

    f32x4 acc[4][2] = {};
    #pragma unroll
    for (int kc = 0; kc < 6; ++kc){
        bf16x8 a[4];
        #pragma unroll
        for (int m = 0; m < 4; ++m)
            a[m] = *reinterpret_cast<const bf16x8*>(&A[(m*16 + lr)*200 + kc*32 + q*8]);
        #pragma unroll
        for (int m = 0; m < 4; ++m)
            #pragma unroll
            for (int n = 0; n < 2; ++n)
                acc[m][n] = __builtin_amdgcn_mfma_f32_16x16x32_bf16(a[m], bb[n][kc], acc[m][n], 0, 0, 0);
    }

    #pragma unroll
    for (int n = 0; n < 2; ++n){
        int c = w*32 + n*16 + lr;
        float s1  = g1[c] * rsqrtf(va1[c] + 1e-5f);
        float sh1 = be1[c] + (bp[c] - mu1[c]) * s1;
        #pragma unroll
        for (int m = 0; m < 4; ++m){
            #pragma unroll
            for (int r = 0; r < 4; ++r){
                int vx = m*16 + q*4 + r;
                float val = fmaxf(fmaf(acc[m][n][r], s1, sh1), 0.f);
                float vp  = __shfl_xor(val, 1);
                if ((lr & 1) == 0){
                    int pk = cellsPk[vx];
                    int multi = pk >> 30;
                    int P = (pk & 0x3fffffff) >> 3, xp7 = pk & 7;
                    short* addr = dbf + (size_t)P*128 + (((c >> 3) ^ xp7) << 3) + (c & 7);
                    unsigned data = (unsigned)(unsigned short)f2bf_s(val)
                                  | ((unsigned)(unsigned short)f2bf_s(vp) << 16);
                    if (!multi){
                        if (data) *reinterpret_cast<unsigned*>(addr) = data;
                    } else {
                        if (data) atomic_pk_add_bf16(addr, data);
                    }
                }
            }
        }
    }
}

// ---------------- conv 3x3 + BN2 + ReLU + mask ----------------
// block: 4y x 64x x 128cout, 512 threads / 8 waves, wave tile 64pos x 64cout
// (m2n2), MFMA 32x32x16.  A: 6 padded rows staged once.  B: half-tap (16 KB)
// ping-pong.  Phase template (T3+T4): {vmcnt(0); s_barrier; sched_barrier;
// STAGE_B(h+1); ds_read+MFMA} — stage issued one full phase before its wait,
// so the per-phase vmcnt(0) is already satisfied (no exposed DMA latency).
__global__ void __launch_bounds__(512, 2)
kconv(const short* __restrict__ dbf, const short* __restrict__ wTs,
      const unsigned char* __restrict__ act, const float* __restrict__ cb,
      const float* __restrict__ g2, const float* __restrict__ be2,
      const float* __restrict__ mu2, const float* __restrict__ va2,
      float* __restrict__ out){
    __shared__ short Atile[6*1056*8];    // 101,376 B
    __shared__ short Bbuf[2][1024*8];    // 2 x 16,384 B
    const int t = threadIdx.x;
    const int bid = (blockIdx.x & 7)*256 + (blockIdx.x >> 3);
    const int b   = bid >> 10;
    const int rem = bid & 1023;
    const int y0  = (rem >> 3) << 2;
    const int x0  = (rem & 7) << 6;

    const int w   = t >> 6, l = t & 63;
    const int yy  = w >> 1, nn = w & 1;
    const int l31 = l & 31, hi = l >> 5;
    const int wbase16 = w*64*16;

    #define STAGE_B(BUF, H) do {                                              \
        const short* gb = wTs + (size_t)((H) >> 1)*16384 + ((H) & 1)*64;      \
        _Pragma("unroll")                                                     \
        for (int j = 0; j < 2; ++j){                                          \
            int S = j*512 + t;                                                \
            const short* gp = gb + (S >> 3)*128 + (S & 7)*8;                  \
            __builtin_amdgcn_global_load_lds(                                 \
                (const __attribute__((address_space(1))) void*)gp,            \
                (__attribute__((address_space(3))) void*)                    \
                    ((char*)Bbuf[BUF] + (size_t)(j*512*16) + wbase16), 16, 0, 0); \
        }                                                                     \
    } while(0)

    // prologue: B half-tap 0 + A (6 padded rows, 6336 slots)
    STAGE_B(0, 0);
    #pragma unroll
    for (int j = 0; j < 13; ++j){
        int S = j*512 + t;
        if (S < 6336){
            int r = S / 1056, s = S - r*1056;
            const short* gp = dbf + ((size_t)((b*514 + (y0 + r))*514 + x0)*16 + s)*8;
            __builtin_amdgcn_global_load_lds(
                (const __attribute__((address_space(1))) void*)gp,
                (__attribute__((address_space(3))) void*)
                    ((char*)Atile + (size_t)(j*512*16) + wbase16), 16, 0, 0);
        }
    }

    f32x16 acc[2][2] = {};
    const int bReadBase = (nn*64 + l31)*64;
    const int bXor = l31 & 7;

    #pragma unroll
    for (int h = 0; h < 18; ++h){
        // all in-flight DMA (stage h, plus A on h=0) landed; cheap in steady state
        asm volatile("s_waitcnt vmcnt(0)" ::: "memory");
        __builtin_amdgcn_s_barrier();
        __builtin_amdgcn_sched_barrier(0);
        if (h < 17) STAGE_B((h+1) & 1, h+1);   // overwrites buf read in phase h-1 — safe post-barrier
        const short* Bc = Bbuf[h & 1];
        const int tap = h >> 1, hh = h & 1;
        const int ky = tap / 3, kx = tap - ky*3;
        const int row = yy + ky;
        const int p0 = l31 + kx, p1 = p0 + 32;
        const int base0 = (row*1056 + p0*16)*8;
        const int base1 = (row*1056 + p1*16)*8;
        const int pk7 = p0 & 7;
        #pragma unroll
        for (int kc = 0; kc < 4; ++kc){
            const int ks  = kc*2 + hi;
            const int q   = ((hh*8 + ks) ^ pk7) << 3;
            const int qb  = (ks ^ bXor) << 3;
            bf16x8 a0 = *reinterpret_cast<const bf16x8*>(&Atile[base0 + q]);
            bf16x8 a1 = *reinterpret_cast<const bf16x8*>(&Atile[base1 + q]);
            bf16x8 b0 = *reinterpret_cast<const bf16x8*>(&Bc[bReadBase + qb]);
            bf16x8 b1 = *reinterpret_cast<const bf16x8*>(&Bc[bReadBase + 2048 + qb]);
            acc[0][0] = __builtin_amdgcn_mfma_f32_32x32x16_bf16(a0, b0, acc[0][0], 0, 0, 0);
            acc[0][1] = __builtin_amdgcn_mfma_f32_32x32x16_bf16(a0, b1, acc[0][1], 0, 0, 0);
            acc[1][0] = __builtin_amdgcn_mfma_f32_32x32x16_bf16(a1, b0, acc[1][0], 0, 0, 0);
            acc[1][1] = __builtin_amdgcn_mfma_f32_32x32x16_bf16(a1, b1, acc[1][1], 0, 0, 0);
        }
    }
    #undef STAGE_B

    const int yg = y0 + yy;
    const size_t rowcell = (size_t)(b*Yq + yg)*Xq + x0;
    #pragma unroll
    for (int ni = 0; ni < 2; ++ni){
        int c = nn*64 + ni*32 + l31;
        float s2  = g2[c] * rsqrtf(va2[c] + 1e-3f);
        float sh2 = be2[c] + (cb[c] - mu2[c]) * s2;
        #pragma unroll
        for (int mi = 0; mi < 2; ++mi){
            #pragma unroll
            for (int r = 0; r < 16; ++r){
                int pos = mi*32 + (r & 3) + ((r >> 2) << 3) + hi*4;
                size_t cell = rowcell + pos;
                float v = act[cell] ? fmaxf(fmaf(acc[mi][ni][r], s2, sh2), 0.f) : 0.f;
                out[cell*128 + c] = v;
            }
        }
    }
}

extern "C" void kernel_launch(void* const* d_in, const int* in_sizes, int n_in,
                              void* d_out, int out_size, void* d_ws, size_t ws_size,
                              hipStream_t stream){
    const float* vf  = (const float*)d_in[0];
    const int*   vc  = (const int*)  d_in[1];
    const float* Wp  = (const float*)d_in[2];
    const float* bp  = (const float*)d_in[3];
    const float* g1  = (const float*)d_in[4];
    const float* be1 = (const float*)d_in[5];
    const float* mu1 = (const float*)d_in[6];
    const float* va1 = (const float*)d_in[7];
    const float* cw  = (const float*)d_in[8];
    const float* cb  = (const float*)d_in[9];
    const float* g2  = (const float*)d_in[10];
    const float* be2 = (const float*)d_in[11];
    const float* mu2 = (const float*)d_in[12];
    const float* va2 = (const float*)d_in[13];
    float* out = (float*)d_out;
    char* ws = (char*)d_ws;

    // ws layout (bytes):
    //   dbf bf16 [2][514][514][128] : 135,268,352 @ 0   (padded, pre-swizzled)
    //   act  u8  [2][512][512]      :     524,288 @ 135,268,352
    //   wTs  bf16 [9][128][128]     :     294,912 @ 135,792,640  (pre-swizzled)
    //   wpT  bf16 [128][192]        :      49,152 @ 136,087,552
    //   cnt  u32 [2][512][512]      :   2,097,152 @ 136,136,704  (end 138,233,856)
    if (ws_size < 138233856ull) return;
    short* dbf = (short*)ws;
    unsigned char* act = (unsigned char*)(ws + 135268352);
    short* wTs = (short*)(ws + 135792640);
    short* wpT = (short*)(ws + 136087552);
    unsigned* cnt = (unsigned*)(ws + 136136704);

    hipMemsetAsync(dbf, 0, 135268352, stream);
    hipMemsetAsync(act, 0, 524288, stream);
    hipMemsetAsync(cnt, 0, 2097152, stream);
    kprep<<<672, 256, 0, stream>>>(cw, Wp, wTs, wpT);
    kcount<<<1563, 256, 0, stream>>>(vc, cnt, act);
    kproj<<<6250, 256, 0, stream>>>(vf, vc, cnt, wpT, bp, g1, be1, mu1, va1, dbf);
    kconv<<<2048, 512, 0, stream>>>(dbf, wTs, act, cb, g2, be2, mu2, va2, out);
}